// Round 1
// baseline (657.071 us; speedup 1.0000x reference)
//
#include <hip/hip_runtime.h>
#include <stdint.h>

#define NODES 50000
#define D 256
#define MP 50048  // rows padded to multiple of 64 (782 * 64)

typedef short bf16x8 __attribute__((ext_vector_type(8)));
typedef float f32x4 __attribute__((ext_vector_type(4)));

__device__ inline unsigned short f2b(float f) {
    unsigned int u = __float_as_uint(f);
    unsigned int r = (u + 0x7fffu + ((u >> 16) & 1u)) >> 16;  // RNE
    return (unsigned short)r;
}

// edge_index dtype auto-detect: reference says int64; harness doc says int32.
// If int64 (little-endian, values < 50000), every odd 32-bit word is 0.
__device__ inline bool ei_is64(const int* ei) {
    return (ei[1] | ei[3] | ei[5] | ei[7]) == 0;
}
__device__ inline int ei_get(const int* __restrict__ ei, long long pos, bool is64) {
    return is64 ? ei[2 * pos] : ei[(int)pos];
}

// ---------------- cast x -> bf16 ----------------
__global__ __launch_bounds__(256) void cast_x_kernel(const float* __restrict__ x,
                                                     unsigned short* __restrict__ xb) {
    int t = blockIdx.x * 256 + threadIdx.x;  // one thread per 4 floats; grid sized exactly
    float4 v = ((const float4*)x)[t];
    unsigned int lo = (unsigned int)f2b(v.x) | ((unsigned int)f2b(v.y) << 16);
    unsigned int hi = (unsigned int)f2b(v.z) | ((unsigned int)f2b(v.w) << 16);
    ((uint2*)xb)[t] = make_uint2(lo, hi);
}

__global__ __launch_bounds__(256) void zero_kernel(int* __restrict__ p, int n) {
    int t = blockIdx.x * 256 + threadIdx.x;
    if (t < n) p[t] = 0;
}

// ---------------- pack W1/W2 into MFMA B-fragment order (bf16) ----------------
// chunk u = (ks*16 + nt)*64 + lane  holds  B[k = ks*32 + (lane>>4)*8 + j][n = nt*16 + (lane&15)], j=0..7
__global__ __launch_bounds__(256) void pack_w_kernel(const float* __restrict__ W1,
                                                     const float* __restrict__ W2,
                                                     unsigned short* __restrict__ P1,
                                                     unsigned short* __restrict__ P2) {
    int t = blockIdx.x * 256 + threadIdx.x;  // 0..16383
    const float* W = (t < 8192) ? W1 : W2;
    unsigned short* P = (t < 8192) ? P1 : P2;
    int u = t & 8191;
    int lane = u & 63, nt = (u >> 6) & 15, s = u >> 10;
    int q = lane >> 4, n = nt * 16 + (lane & 15);
    int kbase = s * 32 + q * 8;
#pragma unroll
    for (int j = 0; j < 8; j++) P[u * 8 + j] = f2b(W[(kbase + j) * D + n]);
}

// ---------------- CSR build: histogram, scan, scatter ----------------
__global__ __launch_bounds__(256) void hist_kernel(const int* __restrict__ ei, int E,
                                                   int* __restrict__ cnt) {
    bool is64 = ei_is64(ei);
    int e = blockIdx.x * 256 + threadIdx.x;
    if (e < E) {
        int d = ei_get(ei, (long long)E + e, is64);
        atomicAdd(&cnt[d], 1);
    }
}

__global__ __launch_bounds__(1024) void scan_kernel(const int* __restrict__ cnt,
                                                    int* __restrict__ offs,
                                                    int* __restrict__ cursor, int n) {
    __shared__ int buf[1024];
    __shared__ int carry_s;
    int t = threadIdx.x;
    if (t == 0) carry_s = 0;
    __syncthreads();
    for (int base = 0; base < n; base += 1024) {
        int i = base + t;
        int v = (i < n) ? cnt[i] : 0;
        buf[t] = v;
        __syncthreads();
        for (int off = 1; off < 1024; off <<= 1) {
            int xv = (t >= off) ? buf[t - off] : 0;
            __syncthreads();
            buf[t] += xv;
            __syncthreads();
        }
        int incl = buf[t];
        int carry = carry_s;
        if (i < n) {
            offs[i] = carry + incl - v;
            cursor[i] = carry + incl - v;
        }
        __syncthreads();
        if (t == 1023) carry_s = carry + incl;
        __syncthreads();
    }
    if (t == 0) offs[n] = carry_s;
}

__global__ __launch_bounds__(256) void scatter_kernel(const int* __restrict__ ei, int E,
                                                      int* __restrict__ cursor,
                                                      int* __restrict__ ebuf) {
    bool is64 = ei_is64(ei);
    int e = blockIdx.x * 256 + threadIdx.x;
    if (e < E) {
        int d = ei_get(ei, (long long)E + e, is64);
        int s = ei_get(ei, (long long)e, is64);
        int pos = atomicAdd(&cursor[d], 1);
        ebuf[pos] = s;
    }
}

// ---------------- aggregation: h0 = (1+eps)*x + sum_{src->i} x[src], bf16 out ----------------
// one wave per node; lane holds 4 of 256 elems; fp32 accumulation
__global__ __launch_bounds__(256) void agg_kernel(const unsigned short* __restrict__ xb,
                                                  const int* __restrict__ offs,
                                                  const int* __restrict__ ebuf,
                                                  const float* __restrict__ eps,
                                                  unsigned short* __restrict__ h0) {
    int wv = (blockIdx.x * 256 + threadIdx.x) >> 6;
    int lane = threadIdx.x & 63;
    if (wv >= NODES) return;
    float scale = 1.0f + eps[0];
    uint2 v = ((const uint2*)(xb + (size_t)wv * D))[lane];
    float a0 = __uint_as_float(v.x << 16) * scale;
    float a1 = __uint_as_float(v.x & 0xffff0000u) * scale;
    float a2 = __uint_as_float(v.y << 16) * scale;
    float a3 = __uint_as_float(v.y & 0xffff0000u) * scale;
    int beg = offs[wv], end = offs[wv + 1];
    for (int base = beg; base < end; base += 64) {
        int id = 0;
        if (base + lane < end) id = ebuf[base + lane];
        int m = min(64, end - base);
        for (int j = 0; j < m; j++) {
            int s = __shfl(id, j);
            uint2 w = *(const uint2*)(xb + (size_t)s * D + lane * 4);
            a0 += __uint_as_float(w.x << 16);
            a1 += __uint_as_float(w.x & 0xffff0000u);
            a2 += __uint_as_float(w.y << 16);
            a3 += __uint_as_float(w.y & 0xffff0000u);
        }
    }
    unsigned int lo = (unsigned int)f2b(a0) | ((unsigned int)f2b(a1) << 16);
    unsigned int hi = (unsigned int)f2b(a2) | ((unsigned int)f2b(a3) << 16);
    ((uint2*)(h0 + (size_t)wv * D))[lane] = make_uint2(lo, hi);
}

// ---------------- GEMM: C[M,256] = A[M,256] @ B + bias, MFMA 16x16x32 bf16 ----------------
// LDS-free: A frags gathered from row-major bf16 (L2/L3-resident), B frags from pre-packed layout.
// block = 4 waves; all waves share 64 rows (mBase), wave w covers cols w*64..w*64+63.
template <int RELU, int OUTBF16>
__global__ __launch_bounds__(256) void gemm_kernel(const unsigned short* __restrict__ A,
                                                   const unsigned short* __restrict__ Bp,
                                                   const float* __restrict__ bias,
                                                   void* __restrict__ out, int Mvalid) {
    int wv = threadIdx.x >> 6;  // n 64-tile, 0..3
    int lane = threadIdx.x & 63;
    int quad = lane >> 4, l16 = lane & 15;
    int mBase = blockIdx.x * 64;
    f32x4 acc[4][4] = {};  // [mi][ni]
    const bf16x8* Bv = (const bf16x8*)Bp;
#pragma unroll
    for (int ks = 0; ks < 8; ks++) {
        bf16x8 a[4], b[4];
#pragma unroll
        for (int mi = 0; mi < 4; mi++) {
            int row = mBase + mi * 16 + l16;
            a[mi] = *(const bf16x8*)(A + (size_t)row * D + ks * 32 + quad * 8);
        }
#pragma unroll
        for (int ni = 0; ni < 4; ni++) {
            int nt = wv * 4 + ni;
            b[ni] = Bv[(ks * 16 + nt) * 64 + lane];
        }
#pragma unroll
        for (int mi = 0; mi < 4; mi++)
#pragma unroll
            for (int ni = 0; ni < 4; ni++)
                acc[mi][ni] =
                    __builtin_amdgcn_mfma_f32_16x16x32_bf16(a[mi], b[ni], acc[mi][ni], 0, 0, 0);
    }
#pragma unroll
    for (int mi = 0; mi < 4; mi++) {
#pragma unroll
        for (int ni = 0; ni < 4; ni++) {
            int col = wv * 64 + ni * 16 + l16;
            float bs = bias[col];
#pragma unroll
            for (int r = 0; r < 4; r++) {
                int row = mBase + mi * 16 + quad * 4 + r;
                if (row < Mvalid) {
                    float v = acc[mi][ni][r] + bs;
                    if (RELU) v = fmaxf(v, 0.0f);
                    if (OUTBF16)
                        ((unsigned short*)out)[(size_t)row * D + col] = f2b(v);
                    else
                        ((float*)out)[(size_t)row * D + col] = v;
                }
            }
        }
    }
}

extern "C" void kernel_launch(void* const* d_in, const int* in_sizes, int n_in,
                              void* d_out, int out_size, void* d_ws, size_t ws_size,
                              hipStream_t stream) {
    const float* x = (const float*)d_in[0];
    const int* ei = (const int*)d_in[1];
    // d_in[2] = edge_attr, unused by forward
    const float* W1 = (const float*)d_in[3];
    const float* b1 = (const float*)d_in[4];
    const float* W2 = (const float*)d_in[5];
    const float* b2 = (const float*)d_in[6];
    const float* eps = (const float*)d_in[7];
    int E = in_sizes[1] / 2;  // 1,600,000

    char* p = (char*)d_ws;
    auto alloc = [&](size_t bytes) {
        char* r = p;
        p += (bytes + 255) & ~(size_t)255;
        return r;
    };
    unsigned short* xb = (unsigned short*)alloc((size_t)MP * D * 2);
    unsigned short* h0 = (unsigned short*)alloc((size_t)MP * D * 2);
    unsigned short* h1 = (unsigned short*)alloc((size_t)MP * D * 2);
    unsigned short* P1 = (unsigned short*)alloc(8192 * 8 * 2);
    unsigned short* P2 = (unsigned short*)alloc(8192 * 8 * 2);
    int* cnt = (int*)alloc((size_t)NODES * 4);
    int* offs = (int*)alloc((size_t)(NODES + 1) * 4);
    int* cursor = (int*)alloc((size_t)NODES * 4);
    int* ebuf = (int*)alloc((size_t)E * 4);

    cast_x_kernel<<<NODES * D / 4 / 256, 256, 0, stream>>>(x, xb);
    zero_kernel<<<(NODES + 255) / 256, 256, 0, stream>>>(cnt, NODES);
    pack_w_kernel<<<64, 256, 0, stream>>>(W1, W2, P1, P2);
    hist_kernel<<<(E + 255) / 256, 256, 0, stream>>>(ei, E, cnt);
    scan_kernel<<<1, 1024, 0, stream>>>(cnt, offs, cursor, NODES);
    scatter_kernel<<<(E + 255) / 256, 256, 0, stream>>>(ei, E, cursor, ebuf);
    agg_kernel<<<(NODES + 3) / 4, 256, 0, stream>>>(xb, offs, ebuf, eps, h0);
    gemm_kernel<1, 1><<<MP / 64, 256, 0, stream>>>(h0, P1, b1, h1, NODES);
    gemm_kernel<0, 0><<<MP / 64, 256, 0, stream>>>(h1, P2, b2, d_out, NODES);
}

// Round 2
// 416.135 us; speedup vs baseline: 1.5790x; 1.5790x over previous
//
#include <hip/hip_runtime.h>
#include <stdint.h>

#define NODES 50000
#define D 256
#define MP 50048   // rows padded to multiple of 64
#define NBUCK 196  // buckets of 256 nodes: dst>>8
#define CAP 10240  // per-bucket capacity in ebufT (mean 8163, sigma 90 -> 23 sigma margin)
#define EPB 4096   // edges per block in partA

typedef short bf16x8 __attribute__((ext_vector_type(8)));
typedef float f32x4 __attribute__((ext_vector_type(4)));

__device__ inline unsigned short f2b(float f) {
    unsigned int u = __float_as_uint(f);
    unsigned int r = (u + 0x7fffu + ((u >> 16) & 1u)) >> 16;  // RNE
    return (unsigned short)r;
}

// edge_index dtype auto-detect: reference says int64; harness may deliver int32.
// If int64 (little-endian, values < 50000), every odd 32-bit word is 0.
__device__ inline bool ei_is64(const int* ei) {
    return (ei[1] | ei[3] | ei[5] | ei[7]) == 0;
}
__device__ inline int ei_get(const int* __restrict__ ei, long long pos, bool is64) {
    return is64 ? ei[2 * pos] : ei[(int)pos];
}

// ---------------- cast x -> bf16 ----------------
__global__ __launch_bounds__(256) void cast_x_kernel(const float* __restrict__ x,
                                                     unsigned short* __restrict__ xb) {
    int t = blockIdx.x * 256 + threadIdx.x;  // one thread per 4 floats; grid sized exactly
    float4 v = ((const float4*)x)[t];
    unsigned int lo = (unsigned int)f2b(v.x) | ((unsigned int)f2b(v.y) << 16);
    unsigned int hi = (unsigned int)f2b(v.z) | ((unsigned int)f2b(v.w) << 16);
    ((uint2*)xb)[t] = make_uint2(lo, hi);
}

__global__ __launch_bounds__(256) void zero_kernel(int* __restrict__ p, int n) {
    int t = blockIdx.x * 256 + threadIdx.x;
    if (t < n) p[t] = 0;
}

// ---------------- pack W1/W2 into MFMA B-fragment order (bf16) ----------------
// chunk u = (ks*16 + nt)*64 + lane  holds  B[k = ks*32 + (lane>>4)*8 + j][n = nt*16 + (lane&15)]
__global__ __launch_bounds__(256) void pack_w_kernel(const float* __restrict__ W1,
                                                     const float* __restrict__ W2,
                                                     unsigned short* __restrict__ P1,
                                                     unsigned short* __restrict__ P2) {
    int t = blockIdx.x * 256 + threadIdx.x;  // 0..16383
    const float* W = (t < 8192) ? W1 : W2;
    unsigned short* P = (t < 8192) ? P1 : P2;
    int u = t & 8191;
    int lane = u & 63, nt = (u >> 6) & 15, s = u >> 10;
    int q = lane >> 4, n = nt * 16 + (lane & 15);
    int kbase = s * 32 + q * 8;
#pragma unroll
    for (int j = 0; j < 8; j++) P[u * 8 + j] = f2b(W[(kbase + j) * D + n]);
}

// ---------------- Pass A: partition edges into 196 dst-buckets ----------------
// word = (dst&255)<<16 | src   (src < 50000 < 2^16)
__global__ __launch_bounds__(256) void partA_kernel(const int* __restrict__ ei, int E,
                                                    int* __restrict__ bcnt,
                                                    unsigned int* __restrict__ ebufT) {
    __shared__ int cnt[256];
    __shared__ int gbase[256];
    __shared__ int lcur[256];
    bool is64 = ei_is64(ei);
    int tid = threadIdx.x;
    cnt[tid] = 0;
    lcur[tid] = 0;
    __syncthreads();
    long long blockStart = (long long)blockIdx.x * EPB;
    unsigned int w[16];
    int bk[16];
#pragma unroll
    for (int r = 0; r < 16; r++) {
        long long e = blockStart + r * 256 + tid;
        bk[r] = -1;
        if (e < E) {
            int src = ei_get(ei, e, is64);
            int dst = ei_get(ei, (long long)E + e, is64);
            bk[r] = dst >> 8;
            w[r] = ((unsigned int)(dst & 255) << 16) | (unsigned int)src;
            atomicAdd(&cnt[bk[r]], 1);
        }
    }
    __syncthreads();
    if (tid < NBUCK && cnt[tid] > 0) gbase[tid] = atomicAdd(&bcnt[tid], cnt[tid]);
    __syncthreads();
#pragma unroll
    for (int r = 0; r < 16; r++) {
        if (bk[r] >= 0) {
            int p = atomicAdd(&lcur[bk[r]], 1);
            ebufT[(size_t)bk[r] * CAP + gbase[bk[r]] + p] = w[r];
        }
    }
}

// ---------------- tiny scan over bucket counts ----------------
__global__ __launch_bounds__(256) void bscan_kernel(const int* __restrict__ bcnt,
                                                    int* __restrict__ bstart,
                                                    int* __restrict__ offs, int E) {
    __shared__ int buf[256];
    int tid = threadIdx.x;
    int v = (tid < NBUCK) ? bcnt[tid] : 0;
    buf[tid] = v;
    __syncthreads();
    for (int off = 1; off < 256; off <<= 1) {
        int xv = (tid >= off) ? buf[tid - off] : 0;
        __syncthreads();
        buf[tid] += xv;
        __syncthreads();
    }
    if (tid < NBUCK) bstart[tid] = buf[tid] - v;
    if (tid == 0) offs[NODES] = E;
}

// ---------------- Pass B: per-bucket node-level sort, builds offs + ebuf ----------------
__global__ __launch_bounds__(256) void partB_kernel(const int* __restrict__ bcnt,
                                                    const int* __restrict__ bstart,
                                                    const unsigned int* __restrict__ ebufT,
                                                    int* __restrict__ offs,
                                                    int* __restrict__ ebuf) {
    __shared__ int ncnt[256];
    __shared__ int ncur[256];
    int b = blockIdx.x, tid = threadIdx.x;
    int n = bcnt[b];
    int base = bstart[b];
    ncnt[tid] = 0;
    __syncthreads();
    const unsigned int* reg = ebufT + (size_t)b * CAP;
    for (int i = tid; i < n; i += 256) {
        unsigned int w = reg[i];
        atomicAdd(&ncnt[w >> 16], 1);
    }
    __syncthreads();
    int v = ncnt[tid];
    ncur[tid] = v;
    __syncthreads();
    for (int off = 1; off < 256; off <<= 1) {
        int xv = (tid >= off) ? ncur[tid - off] : 0;
        __syncthreads();
        ncur[tid] += xv;
        __syncthreads();
    }
    int excl = ncur[tid] - v;
    int node = b * 256 + tid;
    if (node < NODES) offs[node] = base + excl;
    __syncthreads();
    ncur[tid] = excl;
    __syncthreads();
    for (int i = tid; i < n; i += 256) {
        unsigned int w = reg[i];
        int p = atomicAdd(&ncur[w >> 16], 1);
        ebuf[base + p] = (int)(w & 0xffffu);
    }
}

// ---------------- aggregation: h0 = (1+eps)*x + sum_{src->i} x[src], bf16 out ----------------
__global__ __launch_bounds__(256) void agg_kernel(const unsigned short* __restrict__ xb,
                                                  const int* __restrict__ offs,
                                                  const int* __restrict__ ebuf,
                                                  const float* __restrict__ eps,
                                                  unsigned short* __restrict__ h0) {
    int wv = (blockIdx.x * 256 + threadIdx.x) >> 6;
    int lane = threadIdx.x & 63;
    if (wv >= NODES) return;
    float scale = 1.0f + eps[0];
    uint2 v = ((const uint2*)(xb + (size_t)wv * D))[lane];
    float a0 = __uint_as_float(v.x << 16) * scale;
    float a1 = __uint_as_float(v.x & 0xffff0000u) * scale;
    float a2 = __uint_as_float(v.y << 16) * scale;
    float a3 = __uint_as_float(v.y & 0xffff0000u) * scale;
    int beg = offs[wv], end = offs[wv + 1];
    for (int base = beg; base < end; base += 64) {
        int id = 0;
        if (base + lane < end) id = ebuf[base + lane];
        int m = min(64, end - base);
        for (int j = 0; j < m; j++) {
            int s = __shfl(id, j);
            uint2 w = *(const uint2*)(xb + (size_t)s * D + lane * 4);
            a0 += __uint_as_float(w.x << 16);
            a1 += __uint_as_float(w.x & 0xffff0000u);
            a2 += __uint_as_float(w.y << 16);
            a3 += __uint_as_float(w.y & 0xffff0000u);
        }
    }
    unsigned int lo = (unsigned int)f2b(a0) | ((unsigned int)f2b(a1) << 16);
    unsigned int hi = (unsigned int)f2b(a2) | ((unsigned int)f2b(a3) << 16);
    ((uint2*)(h0 + (size_t)wv * D))[lane] = make_uint2(lo, hi);
}

// ---------------- GEMM: C[M,256] = A[M,256] @ B + bias, MFMA 16x16x32 bf16 ----------------
template <int RELU, int OUTBF16>
__global__ __launch_bounds__(256) void gemm_kernel(const unsigned short* __restrict__ A,
                                                   const unsigned short* __restrict__ Bp,
                                                   const float* __restrict__ bias,
                                                   void* __restrict__ out, int Mvalid) {
    int wv = threadIdx.x >> 6;  // n 64-tile, 0..3
    int lane = threadIdx.x & 63;
    int quad = lane >> 4, l16 = lane & 15;
    int mBase = blockIdx.x * 64;
    f32x4 acc[4][4] = {};  // [mi][ni]
    const bf16x8* Bv = (const bf16x8*)Bp;
#pragma unroll
    for (int ks = 0; ks < 8; ks++) {
        bf16x8 a[4], b[4];
#pragma unroll
        for (int mi = 0; mi < 4; mi++) {
            int row = mBase + mi * 16 + l16;
            a[mi] = *(const bf16x8*)(A + (size_t)row * D + ks * 32 + quad * 8);
        }
#pragma unroll
        for (int ni = 0; ni < 4; ni++) {
            int nt = wv * 4 + ni;
            b[ni] = Bv[(ks * 16 + nt) * 64 + lane];
        }
#pragma unroll
        for (int mi = 0; mi < 4; mi++)
#pragma unroll
            for (int ni = 0; ni < 4; ni++)
                acc[mi][ni] =
                    __builtin_amdgcn_mfma_f32_16x16x32_bf16(a[mi], b[ni], acc[mi][ni], 0, 0, 0);
    }
#pragma unroll
    for (int mi = 0; mi < 4; mi++) {
#pragma unroll
        for (int ni = 0; ni < 4; ni++) {
            int col = wv * 64 + ni * 16 + l16;
            float bs = bias[col];
#pragma unroll
            for (int r = 0; r < 4; r++) {
                int row = mBase + mi * 16 + quad * 4 + r;
                if (row < Mvalid) {
                    float v = acc[mi][ni][r] + bs;
                    if (RELU) v = fmaxf(v, 0.0f);
                    if (OUTBF16)
                        ((unsigned short*)out)[(size_t)row * D + col] = f2b(v);
                    else
                        ((float*)out)[(size_t)row * D + col] = v;
                }
            }
        }
    }
}

extern "C" void kernel_launch(void* const* d_in, const int* in_sizes, int n_in,
                              void* d_out, int out_size, void* d_ws, size_t ws_size,
                              hipStream_t stream) {
    const float* x = (const float*)d_in[0];
    const int* ei = (const int*)d_in[1];
    // d_in[2] = edge_attr, unused by forward
    const float* W1 = (const float*)d_in[3];
    const float* b1 = (const float*)d_in[4];
    const float* W2 = (const float*)d_in[5];
    const float* b2 = (const float*)d_in[6];
    const float* eps = (const float*)d_in[7];
    int E = in_sizes[1] / 2;  // 1,600,000

    char* p = (char*)d_ws;
    auto alloc = [&](size_t bytes) {
        char* r = p;
        p += (bytes + 255) & ~(size_t)255;
        return r;
    };
    unsigned short* xb = (unsigned short*)alloc((size_t)MP * D * 2);  // also reused as h1
    unsigned short* h0 = (unsigned short*)alloc((size_t)MP * D * 2);
    unsigned short* P1 = (unsigned short*)alloc(8192 * 8 * 2);
    unsigned short* P2 = (unsigned short*)alloc(8192 * 8 * 2);
    int* bcnt = (int*)alloc((size_t)NBUCK * 4);
    int* bstart = (int*)alloc((size_t)(NBUCK + 1) * 4);
    int* offs = (int*)alloc((size_t)(NODES + 1) * 4);
    int* ebuf = (int*)alloc((size_t)E * 4);
    unsigned int* ebufT = (unsigned int*)alloc((size_t)NBUCK * CAP * 4);
    unsigned short* h1 = xb;  // xb is dead after agg_kernel; reuse for gemm1 output

    cast_x_kernel<<<NODES * D / 4 / 256, 256, 0, stream>>>(x, xb);
    zero_kernel<<<1, 256, 0, stream>>>(bcnt, NBUCK);
    pack_w_kernel<<<64, 256, 0, stream>>>(W1, W2, P1, P2);
    partA_kernel<<<(E + EPB - 1) / EPB, 256, 0, stream>>>(ei, E, bcnt, ebufT);
    bscan_kernel<<<1, 256, 0, stream>>>(bcnt, bstart, offs, E);
    partB_kernel<<<NBUCK, 256, 0, stream>>>(bcnt, bstart, ebufT, offs, ebuf);
    agg_kernel<<<(NODES + 3) / 4, 256, 0, stream>>>(xb, offs, ebuf, eps, h0);
    gemm_kernel<1, 1><<<MP / 64, 256, 0, stream>>>(h0, P1, b1, h1, NODES);
    gemm_kernel<0, 0><<<MP / 64, 256, 0, stream>>>(h1, P2, b2, d_out, NODES);
}

// Round 3
// 379.736 us; speedup vs baseline: 1.7303x; 1.0959x over previous
//
#include <hip/hip_runtime.h>
#include <stdint.h>

#define NODES 50000
#define D 256
#define MP 50048   // rows padded to multiple of 64
#define NBUCK 196  // buckets of 256 nodes: dst>>8
#define CAP 10240  // per-bucket capacity in ebufT (mean 8163, sigma 90 -> 23 sigma margin)
#define EPB 4096   // edges per block in partA
#define HS_LD 264  // fused-gemm LDS row stride in shorts (256 + 8 pad -> 2-way conflicts only)

typedef short bf16x8 __attribute__((ext_vector_type(8)));
typedef float f32x4 __attribute__((ext_vector_type(4)));

__device__ inline unsigned short f2b(float f) {
    unsigned int u = __float_as_uint(f);
    unsigned int r = (u + 0x7fffu + ((u >> 16) & 1u)) >> 16;  // RNE
    return (unsigned short)r;
}

// edge_index dtype auto-detect: reference says int64; harness may deliver int32.
__device__ inline bool ei_is64(const int* ei) {
    return (ei[1] | ei[3] | ei[5] | ei[7]) == 0;
}
__device__ inline int ei_get(const int* __restrict__ ei, long long pos, bool is64) {
    return is64 ? ei[2 * pos] : ei[(int)pos];
}

// ---------------- cast x -> bf16 (+ zero bcnt in block 0) ----------------
__global__ __launch_bounds__(256) void cast_x_kernel(const float* __restrict__ x,
                                                     unsigned short* __restrict__ xb,
                                                     int* __restrict__ bcnt) {
    if (blockIdx.x == 0 && threadIdx.x < NBUCK) bcnt[threadIdx.x] = 0;
    int t = blockIdx.x * 256 + threadIdx.x;  // one thread per 4 floats; grid sized exactly
    float4 v = ((const float4*)x)[t];
    unsigned int lo = (unsigned int)f2b(v.x) | ((unsigned int)f2b(v.y) << 16);
    unsigned int hi = (unsigned int)f2b(v.z) | ((unsigned int)f2b(v.w) << 16);
    ((uint2*)xb)[t] = make_uint2(lo, hi);
}

// ---------------- pack W1/W2 into MFMA B-fragment order (bf16) ----------------
// chunk u = (ks*16 + nt)*64 + lane  holds  B[k = ks*32 + (lane>>4)*8 + j][n = nt*16 + (lane&15)]
__global__ __launch_bounds__(256) void pack_w_kernel(const float* __restrict__ W1,
                                                     const float* __restrict__ W2,
                                                     unsigned short* __restrict__ P1,
                                                     unsigned short* __restrict__ P2) {
    int t = blockIdx.x * 256 + threadIdx.x;  // 0..16383
    const float* W = (t < 8192) ? W1 : W2;
    unsigned short* P = (t < 8192) ? P1 : P2;
    int u = t & 8191;
    int lane = u & 63, nt = (u >> 6) & 15, s = u >> 10;
    int q = lane >> 4, n = nt * 16 + (lane & 15);
    int kbase = s * 32 + q * 8;
#pragma unroll
    for (int j = 0; j < 8; j++) P[u * 8 + j] = f2b(W[(kbase + j) * D + n]);
}

// ---------------- Pass A: partition edges into 196 dst-buckets ----------------
// word = (dst&255)<<16 | src   (src < 50000 < 2^16)
__global__ __launch_bounds__(256) void partA_kernel(const int* __restrict__ ei, int E,
                                                    int* __restrict__ bcnt,
                                                    unsigned int* __restrict__ ebufT) {
    __shared__ int cnt[256];
    __shared__ int gbase[256];
    __shared__ int lcur[256];
    bool is64 = ei_is64(ei);
    int tid = threadIdx.x;
    cnt[tid] = 0;
    lcur[tid] = 0;
    __syncthreads();
    long long blockStart = (long long)blockIdx.x * EPB;
    unsigned int w[16];
    int bk[16];
#pragma unroll
    for (int r = 0; r < 16; r++) {
        long long e = blockStart + r * 256 + tid;
        bk[r] = -1;
        if (e < E) {
            int src = ei_get(ei, e, is64);
            int dst = ei_get(ei, (long long)E + e, is64);
            bk[r] = dst >> 8;
            w[r] = ((unsigned int)(dst & 255) << 16) | (unsigned int)src;
            atomicAdd(&cnt[bk[r]], 1);
        }
    }
    __syncthreads();
    if (tid < NBUCK && cnt[tid] > 0) gbase[tid] = atomicAdd(&bcnt[tid], cnt[tid]);
    __syncthreads();
#pragma unroll
    for (int r = 0; r < 16; r++) {
        if (bk[r] >= 0) {
            int p = atomicAdd(&lcur[bk[r]], 1);
            ebufT[(size_t)bk[r] * CAP + gbase[bk[r]] + p] = w[r];
        }
    }
}

// ---------------- tiny scan over bucket counts ----------------
__global__ __launch_bounds__(256) void bscan_kernel(const int* __restrict__ bcnt,
                                                    int* __restrict__ bstart,
                                                    int* __restrict__ offs, int E) {
    __shared__ int buf[256];
    int tid = threadIdx.x;
    int v = (tid < NBUCK) ? bcnt[tid] : 0;
    buf[tid] = v;
    __syncthreads();
    for (int off = 1; off < 256; off <<= 1) {
        int xv = (tid >= off) ? buf[tid - off] : 0;
        __syncthreads();
        buf[tid] += xv;
        __syncthreads();
    }
    if (tid < NBUCK) bstart[tid] = buf[tid] - v;
    if (tid == 0) offs[NODES] = E;
}

// ---------------- Pass B: per-bucket node-level sort, builds offs + ebuf ----------------
__global__ __launch_bounds__(256) void partB_kernel(const int* __restrict__ bcnt,
                                                    const int* __restrict__ bstart,
                                                    const unsigned int* __restrict__ ebufT,
                                                    int* __restrict__ offs,
                                                    int* __restrict__ ebuf) {
    __shared__ int ncnt[256];
    __shared__ int ncur[256];
    int b = blockIdx.x, tid = threadIdx.x;
    int n = bcnt[b];
    int base = bstart[b];
    ncnt[tid] = 0;
    __syncthreads();
    const unsigned int* reg = ebufT + (size_t)b * CAP;
    for (int i = tid; i < n; i += 256) {
        unsigned int w = reg[i];
        atomicAdd(&ncnt[w >> 16], 1);
    }
    __syncthreads();
    int v = ncnt[tid];
    ncur[tid] = v;
    __syncthreads();
    for (int off = 1; off < 256; off <<= 1) {
        int xv = (tid >= off) ? ncur[tid - off] : 0;
        __syncthreads();
        ncur[tid] += xv;
        __syncthreads();
    }
    int excl = ncur[tid] - v;
    int node = b * 256 + tid;
    if (node < NODES) offs[node] = base + excl;
    __syncthreads();
    ncur[tid] = excl;
    __syncthreads();
    for (int i = tid; i < n; i += 256) {
        unsigned int w = reg[i];
        int p = atomicAdd(&ncur[w >> 16], 1);
        ebuf[base + p] = (int)(w & 0xffffu);
    }
}

// ---------------- aggregation: h0 = (1+eps)*x + sum_{src->i} x[src], bf16 out ----------------
// one wave per node; lanes 0-31 process even edges, 32-63 odd edges (uint4 = 16B/lane).
// 2 independent accumulator banks + x2 unroll -> >=4 edge-row loads in flight per wave.
__device__ inline void upk_add(uint4 w, float* a) {
    a[0] += __uint_as_float(w.x << 16);
    a[1] += __uint_as_float(w.x & 0xffff0000u);
    a[2] += __uint_as_float(w.y << 16);
    a[3] += __uint_as_float(w.y & 0xffff0000u);
    a[4] += __uint_as_float(w.z << 16);
    a[5] += __uint_as_float(w.z & 0xffff0000u);
    a[6] += __uint_as_float(w.w << 16);
    a[7] += __uint_as_float(w.w & 0xffff0000u);
}

__global__ __launch_bounds__(256) void agg_kernel(const unsigned short* __restrict__ xb,
                                                  const int* __restrict__ offs,
                                                  const int* __restrict__ ebuf,
                                                  const float* __restrict__ eps,
                                                  unsigned short* __restrict__ h0) {
    int wv = (blockIdx.x * 256 + threadIdx.x) >> 6;
    int lane = threadIdx.x & 63;
    if (wv >= NODES) return;
    int half = lane >> 5;
    int l32 = lane & 31;
    float aA[8] = {0, 0, 0, 0, 0, 0, 0, 0};
    float aB[8] = {0, 0, 0, 0, 0, 0, 0, 0};
    int beg = offs[wv], end = offs[wv + 1];
    for (int base = beg; base < end; base += 64) {
        int id = 0;
        if (base + lane < end) id = ebuf[base + lane];
        int m = min(64, end - base);
        int j = 0;
        for (; j + 4 <= m; j += 4) {
            int sA = __shfl(id, j + half);
            int sB = __shfl(id, j + 2 + half);
            uint4 wA = *(const uint4*)(xb + (size_t)sA * D + l32 * 8);
            uint4 wB = *(const uint4*)(xb + (size_t)sB * D + l32 * 8);
            upk_add(wA, aA);
            upk_add(wB, aB);
        }
        for (; j + 2 <= m; j += 2) {
            int sA = __shfl(id, j + half);
            uint4 wA = *(const uint4*)(xb + (size_t)sA * D + l32 * 8);
            upk_add(wA, aA);
        }
        if (j < m) {
            int sA = __shfl(id, j);
            if (half == 0) {
                uint4 wA = *(const uint4*)(xb + (size_t)sA * D + l32 * 8);
                upk_add(wA, aA);
            }
        }
    }
    float a[8];
#pragma unroll
    for (int i = 0; i < 8; i++) {
        a[i] = aA[i] + aB[i];
        a[i] += __shfl_xor(a[i], 32);
    }
    if (half == 0) {
        float scale = 1.0f + eps[0];
        uint4 v = *(const uint4*)(xb + (size_t)wv * D + l32 * 8);
        a[0] += scale * __uint_as_float(v.x << 16);
        a[1] += scale * __uint_as_float(v.x & 0xffff0000u);
        a[2] += scale * __uint_as_float(v.y << 16);
        a[3] += scale * __uint_as_float(v.y & 0xffff0000u);
        a[4] += scale * __uint_as_float(v.z << 16);
        a[5] += scale * __uint_as_float(v.z & 0xffff0000u);
        a[6] += scale * __uint_as_float(v.w << 16);
        a[7] += scale * __uint_as_float(v.w & 0xffff0000u);
        uint4 o;
        o.x = (unsigned int)f2b(a[0]) | ((unsigned int)f2b(a[1]) << 16);
        o.y = (unsigned int)f2b(a[2]) | ((unsigned int)f2b(a[3]) << 16);
        o.z = (unsigned int)f2b(a[4]) | ((unsigned int)f2b(a[5]) << 16);
        o.w = (unsigned int)f2b(a[6]) | ((unsigned int)f2b(a[7]) << 16);
        ((uint4*)(h0 + (size_t)wv * D))[l32] = o;
    }
}

// ---------------- fused MLP: out = relu(A@W1+b1)@W2 + b2 ----------------
// block = 4 waves, 64 rows; stage 1 -> bf16 tile in padded LDS; stage 2 -> fp32 out.
__global__ __launch_bounds__(256) void gemm_fused_kernel(const unsigned short* __restrict__ A,
                                                         const unsigned short* __restrict__ P1,
                                                         const float* __restrict__ b1,
                                                         const unsigned short* __restrict__ P2,
                                                         const float* __restrict__ b2,
                                                         float* __restrict__ out, int Mvalid) {
    __shared__ unsigned short hs[64 * HS_LD];  // 33 KB
    int wv = threadIdx.x >> 6;  // n 64-tile, 0..3
    int lane = threadIdx.x & 63;
    int quad = lane >> 4, l16 = lane & 15;
    int mBase = blockIdx.x * 64;
    const bf16x8* B1v = (const bf16x8*)P1;
    const bf16x8* B2v = (const bf16x8*)P2;

    // ---- stage 1: h = relu(A@W1+b1) -> LDS (bf16) ----
    {
        f32x4 acc[4][4] = {};
#pragma unroll
        for (int ks = 0; ks < 8; ks++) {
            bf16x8 af[4], bf[4];
#pragma unroll
            for (int mi = 0; mi < 4; mi++) {
                int row = mBase + mi * 16 + l16;
                af[mi] = *(const bf16x8*)(A + (size_t)row * D + ks * 32 + quad * 8);
            }
#pragma unroll
            for (int ni = 0; ni < 4; ni++) bf[ni] = B1v[(ks * 16 + wv * 4 + ni) * 64 + lane];
#pragma unroll
            for (int mi = 0; mi < 4; mi++)
#pragma unroll
                for (int ni = 0; ni < 4; ni++)
                    acc[mi][ni] = __builtin_amdgcn_mfma_f32_16x16x32_bf16(af[mi], bf[ni],
                                                                          acc[mi][ni], 0, 0, 0);
        }
#pragma unroll
        for (int mi = 0; mi < 4; mi++)
#pragma unroll
            for (int ni = 0; ni < 4; ni++) {
                int col = wv * 64 + ni * 16 + l16;
                float bs = b1[col];
#pragma unroll
                for (int r = 0; r < 4; r++) {
                    int rl = mi * 16 + quad * 4 + r;
                    hs[rl * HS_LD + col] = f2b(fmaxf(acc[mi][ni][r] + bs, 0.0f));
                }
            }
    }
    __syncthreads();

    // ---- stage 2: out = h@W2 + b2 (A-frags from LDS) ----
    f32x4 acc[4][4] = {};
#pragma unroll
    for (int ks = 0; ks < 8; ks++) {
        bf16x8 af[4], bf[4];
#pragma unroll
        for (int mi = 0; mi < 4; mi++)
            af[mi] = *(const bf16x8*)(hs + (mi * 16 + l16) * HS_LD + ks * 32 + quad * 8);
#pragma unroll
        for (int ni = 0; ni < 4; ni++) bf[ni] = B2v[(ks * 16 + wv * 4 + ni) * 64 + lane];
#pragma unroll
        for (int mi = 0; mi < 4; mi++)
#pragma unroll
            for (int ni = 0; ni < 4; ni++)
                acc[mi][ni] =
                    __builtin_amdgcn_mfma_f32_16x16x32_bf16(af[mi], bf[ni], acc[mi][ni], 0, 0, 0);
    }
#pragma unroll
    for (int mi = 0; mi < 4; mi++)
#pragma unroll
        for (int ni = 0; ni < 4; ni++) {
            int col = wv * 64 + ni * 16 + l16;
            float bs = b2[col];
#pragma unroll
            for (int r = 0; r < 4; r++) {
                int row = mBase + mi * 16 + quad * 4 + r;
                if (row < Mvalid) out[(size_t)row * D + col] = acc[mi][ni][r] + bs;
            }
        }
}

extern "C" void kernel_launch(void* const* d_in, const int* in_sizes, int n_in,
                              void* d_out, int out_size, void* d_ws, size_t ws_size,
                              hipStream_t stream) {
    const float* x = (const float*)d_in[0];
    const int* ei = (const int*)d_in[1];
    // d_in[2] = edge_attr, unused by forward
    const float* W1 = (const float*)d_in[3];
    const float* b1 = (const float*)d_in[4];
    const float* W2 = (const float*)d_in[5];
    const float* b2 = (const float*)d_in[6];
    const float* eps = (const float*)d_in[7];
    int E = in_sizes[1] / 2;  // 1,600,000

    char* p = (char*)d_ws;
    auto alloc = [&](size_t bytes) {
        char* r = p;
        p += (bytes + 255) & ~(size_t)255;
        return r;
    };
    unsigned short* xb = (unsigned short*)alloc((size_t)MP * D * 2);
    unsigned short* h0 = (unsigned short*)alloc((size_t)MP * D * 2);
    unsigned short* P1 = (unsigned short*)alloc(8192 * 8 * 2);
    unsigned short* P2 = (unsigned short*)alloc(8192 * 8 * 2);
    int* bcnt = (int*)alloc((size_t)NBUCK * 4);
    int* bstart = (int*)alloc((size_t)(NBUCK + 1) * 4);
    int* offs = (int*)alloc((size_t)(NODES + 1) * 4);
    int* ebuf = (int*)alloc((size_t)E * 4);
    unsigned int* ebufT = (unsigned int*)alloc((size_t)NBUCK * CAP * 4);

    cast_x_kernel<<<NODES * D / 4 / 256, 256, 0, stream>>>(x, xb, bcnt);
    pack_w_kernel<<<64, 256, 0, stream>>>(W1, W2, P1, P2);
    partA_kernel<<<(E + EPB - 1) / EPB, 256, 0, stream>>>(ei, E, bcnt, ebufT);
    bscan_kernel<<<1, 256, 0, stream>>>(bcnt, bstart, offs, E);
    partB_kernel<<<NBUCK, 256, 0, stream>>>(bcnt, bstart, ebufT, offs, ebuf);
    agg_kernel<<<(NODES + 3) / 4, 256, 0, stream>>>(xb, offs, ebuf, eps, h0);
    gemm_fused_kernel<<<MP / 64, 256, 0, stream>>>(h0, P1, b1, P2, b2, (float*)d_out, NODES);
}

// Round 4
// 364.394 us; speedup vs baseline: 1.8032x; 1.0421x over previous
//
#include <hip/hip_runtime.h>
#include <stdint.h>

#define NODES 50000
#define D 256
#define MP 50048   // rows padded to multiple of 64
#define NBUCK 196  // buckets of 256 nodes: dst>>8
#define CAP 10240  // per-bucket capacity in ebufT (mean 8163, sigma 90 -> 23 sigma margin)
#define EPB 4096   // edges per block in partA
#define HS_LD 264  // fused-gemm LDS row stride in shorts (256 + 8 pad -> 2-way conflicts only)
#define CAST_BLOCKS 12500  // NODES*D/4/256

typedef short bf16x8 __attribute__((ext_vector_type(8)));
typedef float f32x4 __attribute__((ext_vector_type(4)));

__device__ inline unsigned short f2b(float f) {
    unsigned int u = __float_as_uint(f);
    unsigned int r = (u + 0x7fffu + ((u >> 16) & 1u)) >> 16;  // RNE
    return (unsigned short)r;
}

// edge_index dtype auto-detect: reference says int64; harness may deliver int32.
__device__ inline bool ei_is64(const int* ei) {
    return (ei[1] | ei[3] | ei[5] | ei[7]) == 0;
}
__device__ inline int ei_get(const int* __restrict__ ei, long long pos, bool is64) {
    return is64 ? ei[2 * pos] : ei[(int)pos];
}

// ---------------- prep: cast x -> bf16, zero bcnt, pack W1/W2 (fused) ----------------
// pack layout: chunk u = (ks*16 + nt)*64 + lane holds B[k = ks*32 + (lane>>4)*8 + j][n = nt*16 + (lane&15)]
__global__ __launch_bounds__(256) void prep_kernel(const float* __restrict__ x,
                                                   unsigned short* __restrict__ xb,
                                                   int* __restrict__ bcnt,
                                                   const float* __restrict__ W1,
                                                   const float* __restrict__ W2,
                                                   unsigned short* __restrict__ P1,
                                                   unsigned short* __restrict__ P2) {
    int blk = blockIdx.x;
    if (blk < CAST_BLOCKS) {
        if (blk == 0 && threadIdx.x < NBUCK) bcnt[threadIdx.x] = 0;
        int t = blk * 256 + threadIdx.x;  // one thread per 4 floats
        float4 v = ((const float4*)x)[t];
        unsigned int lo = (unsigned int)f2b(v.x) | ((unsigned int)f2b(v.y) << 16);
        unsigned int hi = (unsigned int)f2b(v.z) | ((unsigned int)f2b(v.w) << 16);
        ((uint2*)xb)[t] = make_uint2(lo, hi);
    } else {
        int t = (blk - CAST_BLOCKS) * 256 + threadIdx.x;  // 0..16383
        const float* W = (t < 8192) ? W1 : W2;
        unsigned short* P = (t < 8192) ? P1 : P2;
        int u = t & 8191;
        int lane = u & 63, nt = (u >> 6) & 15, s = u >> 10;
        int q = lane >> 4, n = nt * 16 + (lane & 15);
        int kbase = s * 32 + q * 8;
#pragma unroll
        for (int j = 0; j < 8; j++) P[u * 8 + j] = f2b(W[(kbase + j) * D + n]);
    }
}

// ---------------- Pass A: partition edges into 196 dst-buckets ----------------
// word = (dst&255)<<16 | src   (src < 50000 < 2^16)
__global__ __launch_bounds__(256) void partA_kernel(const int* __restrict__ ei, int E,
                                                    int* __restrict__ bcnt,
                                                    unsigned int* __restrict__ ebufT) {
    __shared__ int cnt[256];
    __shared__ int gbase[256];
    __shared__ int lcur[256];
    bool is64 = ei_is64(ei);
    int tid = threadIdx.x;
    cnt[tid] = 0;
    lcur[tid] = 0;
    __syncthreads();
    long long pairBase = ((long long)blockIdx.x * EPB) >> 1;
    unsigned int w[16];
    int bk[16];
#pragma unroll
    for (int r = 0; r < 8; r++) {
        long long pp = pairBase + (long long)r * 256 + tid;
        long long e0 = pp * 2;
        int s0 = 0, s1 = 0, d0 = 0, d1 = 0;
        bool v1 = (e0 + 1 < E), v0 = (e0 < E);
        if (v1) {
            if (is64) {
                uint4 sv = *(const uint4*)(ei + 4 * pp);
                uint4 dv = *(const uint4*)(ei + (size_t)2 * E + 4 * pp);
                s0 = (int)sv.x; s1 = (int)sv.z; d0 = (int)dv.x; d1 = (int)dv.z;
            } else {
                uint2 sv = *(const uint2*)(ei + 2 * pp);
                uint2 dv = *(const uint2*)(ei + (size_t)E + 2 * pp);
                s0 = (int)sv.x; s1 = (int)sv.y; d0 = (int)dv.x; d1 = (int)dv.y;
            }
        } else if (v0) {
            s0 = ei_get(ei, e0, is64);
            d0 = ei_get(ei, (long long)E + e0, is64);
        }
        bk[2 * r] = v0 ? (d0 >> 8) : -1;
        bk[2 * r + 1] = v1 ? (d1 >> 8) : -1;
        w[2 * r] = ((unsigned int)(d0 & 255) << 16) | (unsigned int)s0;
        w[2 * r + 1] = ((unsigned int)(d1 & 255) << 16) | (unsigned int)s1;
        if (v0) atomicAdd(&cnt[bk[2 * r]], 1);
        if (v1) atomicAdd(&cnt[bk[2 * r + 1]], 1);
    }
    __syncthreads();
    if (tid < NBUCK && cnt[tid] > 0) gbase[tid] = atomicAdd(&bcnt[tid], cnt[tid]);
    __syncthreads();
#pragma unroll
    for (int r = 0; r < 16; r++) {
        if (bk[r] >= 0) {
            int p = atomicAdd(&lcur[bk[r]], 1);
            ebufT[(size_t)bk[r] * CAP + gbase[bk[r]] + p] = w[r];
        }
    }
}

// ---------------- tiny scan over bucket counts ----------------
__global__ __launch_bounds__(256) void bscan_kernel(const int* __restrict__ bcnt,
                                                    int* __restrict__ bstart,
                                                    int* __restrict__ offs, int E) {
    __shared__ int buf[256];
    int tid = threadIdx.x;
    int v = (tid < NBUCK) ? bcnt[tid] : 0;
    buf[tid] = v;
    __syncthreads();
    for (int off = 1; off < 256; off <<= 1) {
        int xv = (tid >= off) ? buf[tid - off] : 0;
        __syncthreads();
        buf[tid] += xv;
        __syncthreads();
    }
    if (tid < NBUCK) bstart[tid] = buf[tid] - v;
    if (tid == 0) offs[NODES] = E;
}

// ---------------- Pass B: per-bucket node-level sort, builds offs + ebuf ----------------
__global__ __launch_bounds__(1024) void partB_kernel(const int* __restrict__ bcnt,
                                                     const int* __restrict__ bstart,
                                                     const unsigned int* __restrict__ ebufT,
                                                     int* __restrict__ offs,
                                                     int* __restrict__ ebuf) {
    __shared__ int ncnt[256];
    __shared__ int ncur[256];
    int b = blockIdx.x, tid = threadIdx.x;
    int n = bcnt[b];
    int base = bstart[b];
    if (tid < 256) ncnt[tid] = 0;
    __syncthreads();
    const unsigned int* reg = ebufT + (size_t)b * CAP;
    for (int i = tid; i < n; i += 1024) atomicAdd(&ncnt[reg[i] >> 16], 1);
    __syncthreads();
    int v = 0;
    if (tid < 256) {
        v = ncnt[tid];
        ncur[tid] = v;
    }
    __syncthreads();
    for (int off = 1; off < 256; off <<= 1) {
        int xv = 0;
        if (tid < 256 && tid >= off) xv = ncur[tid - off];
        __syncthreads();
        if (tid < 256) ncur[tid] += xv;
        __syncthreads();
    }
    if (tid < 256) {
        int excl = ncur[tid] - v;
        int node = b * 256 + tid;
        if (node < NODES) offs[node] = base + excl;
        ncur[tid] = excl;
    }
    __syncthreads();
    for (int i = tid; i < n; i += 1024) {
        unsigned int w = reg[i];
        int p = atomicAdd(&ncur[w >> 16], 1);
        ebuf[base + p] = (int)(w & 0xffffu);
    }
}

// ---------------- aggregation: h0 = (1+eps)*x + sum_{src->i} x[src], bf16 out ----------------
// one wave per node; lanes 0-31 = even edges, 32-63 = odd edges (uint4 = 16B/lane).
// No shfl: each half broadcast-loads its edge id. 4 row-loads in flight per iteration.
__device__ inline void upk_add(uint4 w, float* a) {
    a[0] += __uint_as_float(w.x << 16);
    a[1] += __uint_as_float(w.x & 0xffff0000u);
    a[2] += __uint_as_float(w.y << 16);
    a[3] += __uint_as_float(w.y & 0xffff0000u);
    a[4] += __uint_as_float(w.z << 16);
    a[5] += __uint_as_float(w.z & 0xffff0000u);
    a[6] += __uint_as_float(w.w << 16);
    a[7] += __uint_as_float(w.w & 0xffff0000u);
}

__global__ __launch_bounds__(256) void agg_kernel(const unsigned short* __restrict__ xb,
                                                  const int* __restrict__ offs,
                                                  const int* __restrict__ ebuf,
                                                  const float* __restrict__ eps,
                                                  unsigned short* __restrict__ h0) {
    int wv = (blockIdx.x * 256 + threadIdx.x) >> 6;
    int lane = threadIdx.x & 63;
    if (wv >= NODES) return;
    int half = lane >> 5;
    int l32 = lane & 31;
    float aA[8] = {0, 0, 0, 0, 0, 0, 0, 0};
    float aB[8] = {0, 0, 0, 0, 0, 0, 0, 0};
    int beg = offs[wv], end = offs[wv + 1];
    int j = beg;
    for (; j + 8 <= end; j += 8) {
        int i0 = ebuf[j + half];
        int i1 = ebuf[j + 2 + half];
        int i2 = ebuf[j + 4 + half];
        int i3 = ebuf[j + 6 + half];
        uint4 w0 = *(const uint4*)(xb + (size_t)i0 * D + l32 * 8);
        uint4 w1 = *(const uint4*)(xb + (size_t)i1 * D + l32 * 8);
        uint4 w2 = *(const uint4*)(xb + (size_t)i2 * D + l32 * 8);
        uint4 w3 = *(const uint4*)(xb + (size_t)i3 * D + l32 * 8);
        upk_add(w0, aA);
        upk_add(w1, aB);
        upk_add(w2, aA);
        upk_add(w3, aB);
    }
    for (; j + 2 <= end; j += 2) {
        int i0 = ebuf[j + half];
        uint4 w0 = *(const uint4*)(xb + (size_t)i0 * D + l32 * 8);
        upk_add(w0, aA);
    }
    if (j < end && half == 0) {
        int i0 = ebuf[j];
        uint4 w0 = *(const uint4*)(xb + (size_t)i0 * D + l32 * 8);
        upk_add(w0, aA);
    }
    float a[8];
#pragma unroll
    for (int i = 0; i < 8; i++) {
        a[i] = aA[i] + aB[i];
        a[i] += __shfl_xor(a[i], 32);
    }
    if (half == 0) {
        float scale = 1.0f + eps[0];
        uint4 v = *(const uint4*)(xb + (size_t)wv * D + l32 * 8);
        a[0] += scale * __uint_as_float(v.x << 16);
        a[1] += scale * __uint_as_float(v.x & 0xffff0000u);
        a[2] += scale * __uint_as_float(v.y << 16);
        a[3] += scale * __uint_as_float(v.y & 0xffff0000u);
        a[4] += scale * __uint_as_float(v.z << 16);
        a[5] += scale * __uint_as_float(v.z & 0xffff0000u);
        a[6] += scale * __uint_as_float(v.w << 16);
        a[7] += scale * __uint_as_float(v.w & 0xffff0000u);
        uint4 o;
        o.x = (unsigned int)f2b(a[0]) | ((unsigned int)f2b(a[1]) << 16);
        o.y = (unsigned int)f2b(a[2]) | ((unsigned int)f2b(a[3]) << 16);
        o.z = (unsigned int)f2b(a[4]) | ((unsigned int)f2b(a[5]) << 16);
        o.w = (unsigned int)f2b(a[6]) | ((unsigned int)f2b(a[7]) << 16);
        ((uint4*)(h0 + (size_t)wv * D))[l32] = o;
    }
}

// ---------------- fused MLP: out = relu(A@W1+b1)@W2 + b2 ----------------
// block = 4 waves, 64 rows; stage 1 -> bf16 tile in padded LDS; stage 2 -> fp32 out.
__global__ __launch_bounds__(256) void gemm_fused_kernel(const unsigned short* __restrict__ A,
                                                         const unsigned short* __restrict__ P1,
                                                         const float* __restrict__ b1,
                                                         const unsigned short* __restrict__ P2,
                                                         const float* __restrict__ b2,
                                                         float* __restrict__ out, int Mvalid) {
    __shared__ unsigned short hs[64 * HS_LD];  // 33 KB
    int wv = threadIdx.x >> 6;  // n 64-tile, 0..3
    int lane = threadIdx.x & 63;
    int quad = lane >> 4, l16 = lane & 15;
    int mBase = blockIdx.x * 64;
    const bf16x8* B1v = (const bf16x8*)P1;
    const bf16x8* B2v = (const bf16x8*)P2;

    // ---- stage 1: h = relu(A@W1+b1) -> LDS (bf16) ----
    {
        f32x4 acc[4][4] = {};
#pragma unroll
        for (int ks = 0; ks < 8; ks++) {
            bf16x8 af[4], bf[4];
#pragma unroll
            for (int mi = 0; mi < 4; mi++) {
                int row = mBase + mi * 16 + l16;
                af[mi] = *(const bf16x8*)(A + (size_t)row * D + ks * 32 + quad * 8);
            }
#pragma unroll
            for (int ni = 0; ni < 4; ni++) bf[ni] = B1v[(ks * 16 + wv * 4 + ni) * 64 + lane];
#pragma unroll
            for (int mi = 0; mi < 4; mi++)
#pragma unroll
                for (int ni = 0; ni < 4; ni++)
                    acc[mi][ni] = __builtin_amdgcn_mfma_f32_16x16x32_bf16(af[mi], bf[ni],
                                                                          acc[mi][ni], 0, 0, 0);
        }
#pragma unroll
        for (int mi = 0; mi < 4; mi++)
#pragma unroll
            for (int ni = 0; ni < 4; ni++) {
                int col = wv * 64 + ni * 16 + l16;
                float bs = b1[col];
#pragma unroll
                for (int r = 0; r < 4; r++) {
                    int rl = mi * 16 + quad * 4 + r;
                    hs[rl * HS_LD + col] = f2b(fmaxf(acc[mi][ni][r] + bs, 0.0f));
                }
            }
    }
    __syncthreads();

    // ---- stage 2: out = h@W2 + b2 (A-frags from LDS) ----
    f32x4 acc[4][4] = {};
#pragma unroll
    for (int ks = 0; ks < 8; ks++) {
        bf16x8 af[4], bf[4];
#pragma unroll
        for (int mi = 0; mi < 4; mi++)
            af[mi] = *(const bf16x8*)(hs + (mi * 16 + l16) * HS_LD + ks * 32 + quad * 8);
#pragma unroll
        for (int ni = 0; ni < 4; ni++) bf[ni] = B2v[(ks * 16 + wv * 4 + ni) * 64 + lane];
#pragma unroll
        for (int mi = 0; mi < 4; mi++)
#pragma unroll
            for (int ni = 0; ni < 4; ni++)
                acc[mi][ni] =
                    __builtin_amdgcn_mfma_f32_16x16x32_bf16(af[mi], bf[ni], acc[mi][ni], 0, 0, 0);
    }
#pragma unroll
    for (int mi = 0; mi < 4; mi++)
#pragma unroll
        for (int ni = 0; ni < 4; ni++) {
            int col = wv * 64 + ni * 16 + l16;
            float bs = b2[col];
#pragma unroll
            for (int r = 0; r < 4; r++) {
                int row = mBase + mi * 16 + quad * 4 + r;
                if (row < Mvalid) out[(size_t)row * D + col] = acc[mi][ni][r] + bs;
            }
        }
}

extern "C" void kernel_launch(void* const* d_in, const int* in_sizes, int n_in,
                              void* d_out, int out_size, void* d_ws, size_t ws_size,
                              hipStream_t stream) {
    const float* x = (const float*)d_in[0];
    const int* ei = (const int*)d_in[1];
    // d_in[2] = edge_attr, unused by forward
    const float* W1 = (const float*)d_in[3];
    const float* b1 = (const float*)d_in[4];
    const float* W2 = (const float*)d_in[5];
    const float* b2 = (const float*)d_in[6];
    const float* eps = (const float*)d_in[7];
    int E = in_sizes[1] / 2;  // 1,600,000

    char* p = (char*)d_ws;
    auto alloc = [&](size_t bytes) {
        char* r = p;
        p += (bytes + 255) & ~(size_t)255;
        return r;
    };
    unsigned short* xb = (unsigned short*)alloc((size_t)MP * D * 2);
    unsigned short* h0 = (unsigned short*)alloc((size_t)MP * D * 2);
    unsigned short* P1 = (unsigned short*)alloc(8192 * 8 * 2);
    unsigned short* P2 = (unsigned short*)alloc(8192 * 8 * 2);
    int* bcnt = (int*)alloc((size_t)NBUCK * 4);
    int* bstart = (int*)alloc((size_t)(NBUCK + 1) * 4);
    int* offs = (int*)alloc((size_t)(NODES + 1) * 4);
    int* ebuf = (int*)alloc((size_t)E * 4);
    unsigned int* ebufT = (unsigned int*)alloc((size_t)NBUCK * CAP * 4);

    prep_kernel<<<CAST_BLOCKS + 64, 256, 0, stream>>>(x, xb, bcnt, W1, W2, P1, P2);
    partA_kernel<<<(E + EPB - 1) / EPB, 256, 0, stream>>>(ei, E, bcnt, ebufT);
    bscan_kernel<<<1, 256, 0, stream>>>(bcnt, bstart, offs, E);
    partB_kernel<<<NBUCK, 1024, 0, stream>>>(bcnt, bstart, ebufT, offs, ebuf);
    agg_kernel<<<(NODES + 3) / 4, 256, 0, stream>>>(xb, offs, ebuf, eps, h0);
    gemm_fused_kernel<<<MP / 64, 256, 0, stream>>>(h0, P1, b1, P2, b2, (float*)d_out, NODES);
}

// Round 5
// 357.872 us; speedup vs baseline: 1.8361x; 1.0182x over previous
//
#include <hip/hip_runtime.h>
#include <stdint.h>

#define NODES 50000
#define D 256
#define MP 50048   // rows padded to multiple of 64
#define NBUCK 196  // buckets of 256 nodes: dst>>8
#define CAP 10240  // per-bucket capacity in ebufT (mean 8163, sigma 90 -> 23 sigma margin)
#define EPB 4096   // edges per block in partA
#define HS_LD 264  // fused-gemm LDS row stride in shorts (256 + 8 pad -> 2-way conflicts only)
#define CAST_BLOCKS 12500  // NODES*D/4/256

typedef short bf16x8 __attribute__((ext_vector_type(8)));
typedef float f32x4 __attribute__((ext_vector_type(4)));

__device__ inline unsigned short f2b(float f) {
    unsigned int u = __float_as_uint(f);
    unsigned int r = (u + 0x7fffu + ((u >> 16) & 1u)) >> 16;  // RNE
    return (unsigned short)r;
}

// edge_index dtype auto-detect: reference says int64; harness may deliver int32.
__device__ inline bool ei_is64(const int* ei) {
    return (ei[1] | ei[3] | ei[5] | ei[7]) == 0;
}
__device__ inline int ei_get(const int* __restrict__ ei, long long pos, bool is64) {
    return is64 ? ei[2 * pos] : ei[(int)pos];
}

// ---------------- prep: cast x -> bf16, zero bcnt, offs[NODES]=E, pack W1/W2 ----------------
// pack layout: chunk u = (ks*16 + nt)*64 + lane holds B[k = ks*32 + (lane>>4)*8 + j][n = nt*16 + (lane&15)]
__global__ __launch_bounds__(256) void prep_kernel(const float* __restrict__ x,
                                                   unsigned short* __restrict__ xb,
                                                   int* __restrict__ bcnt,
                                                   const float* __restrict__ W1,
                                                   const float* __restrict__ W2,
                                                   unsigned short* __restrict__ P1,
                                                   unsigned short* __restrict__ P2,
                                                   int* __restrict__ offs, int E) {
    int blk = blockIdx.x;
    if (blk < CAST_BLOCKS) {
        if (blk == 0 && threadIdx.x < NBUCK) bcnt[threadIdx.x] = 0;
        if (blk == 0 && threadIdx.x == 0) offs[NODES] = E;
        int t = blk * 256 + threadIdx.x;  // one thread per 4 floats
        float4 v = ((const float4*)x)[t];
        unsigned int lo = (unsigned int)f2b(v.x) | ((unsigned int)f2b(v.y) << 16);
        unsigned int hi = (unsigned int)f2b(v.z) | ((unsigned int)f2b(v.w) << 16);
        ((uint2*)xb)[t] = make_uint2(lo, hi);
    } else {
        int t = (blk - CAST_BLOCKS) * 256 + threadIdx.x;  // 0..16383
        const float* W = (t < 8192) ? W1 : W2;
        unsigned short* P = (t < 8192) ? P1 : P2;
        int u = t & 8191;
        int lane = u & 63, nt = (u >> 6) & 15, s = u >> 10;
        int q = lane >> 4, n = nt * 16 + (lane & 15);
        int kbase = s * 32 + q * 8;
#pragma unroll
        for (int j = 0; j < 8; j++) P[u * 8 + j] = f2b(W[(kbase + j) * D + n]);
    }
}

// ---------------- Pass A: partition edges into 196 dst-buckets ----------------
// word = (dst&255)<<16 | src   (src < 50000 < 2^16)
__global__ __launch_bounds__(256) void partA_kernel(const int* __restrict__ ei, int E,
                                                    int* __restrict__ bcnt,
                                                    unsigned int* __restrict__ ebufT) {
    __shared__ int cnt[256];
    __shared__ int gbase[256];
    __shared__ int lcur[256];
    bool is64 = ei_is64(ei);
    int tid = threadIdx.x;
    cnt[tid] = 0;
    lcur[tid] = 0;
    __syncthreads();
    long long pairBase = ((long long)blockIdx.x * EPB) >> 1;
    unsigned int w[16];
    int bk[16];
#pragma unroll
    for (int r = 0; r < 8; r++) {
        long long pp = pairBase + (long long)r * 256 + tid;
        long long e0 = pp * 2;
        int s0 = 0, s1 = 0, d0 = 0, d1 = 0;
        bool v1 = (e0 + 1 < E), v0 = (e0 < E);
        if (v1) {
            if (is64) {
                uint4 sv = *(const uint4*)(ei + 4 * pp);
                uint4 dv = *(const uint4*)(ei + (size_t)2 * E + 4 * pp);
                s0 = (int)sv.x; s1 = (int)sv.z; d0 = (int)dv.x; d1 = (int)dv.z;
            } else {
                uint2 sv = *(const uint2*)(ei + 2 * pp);
                uint2 dv = *(const uint2*)(ei + (size_t)E + 2 * pp);
                s0 = (int)sv.x; s1 = (int)sv.y; d0 = (int)dv.x; d1 = (int)dv.y;
            }
        } else if (v0) {
            s0 = ei_get(ei, e0, is64);
            d0 = ei_get(ei, (long long)E + e0, is64);
        }
        bk[2 * r] = v0 ? (d0 >> 8) : -1;
        bk[2 * r + 1] = v1 ? (d1 >> 8) : -1;
        w[2 * r] = ((unsigned int)(d0 & 255) << 16) | (unsigned int)s0;
        w[2 * r + 1] = ((unsigned int)(d1 & 255) << 16) | (unsigned int)s1;
        if (v0) atomicAdd(&cnt[bk[2 * r]], 1);
        if (v1) atomicAdd(&cnt[bk[2 * r + 1]], 1);
    }
    __syncthreads();
    if (tid < NBUCK && cnt[tid] > 0) gbase[tid] = atomicAdd(&bcnt[tid], cnt[tid]);
    __syncthreads();
#pragma unroll
    for (int r = 0; r < 16; r++) {
        if (bk[r] >= 0) {
            int p = atomicAdd(&lcur[bk[r]], 1);
            ebufT[(size_t)bk[r] * CAP + gbase[bk[r]] + p] = w[r];
        }
    }
}

// ---------------- Pass B: per-bucket node sort; bucket prefix computed in-block ----------------
__global__ __launch_bounds__(1024) void partB_kernel(const int* __restrict__ bcnt,
                                                     const unsigned int* __restrict__ ebufT,
                                                     int* __restrict__ offs,
                                                     int* __restrict__ ebuf) {
    __shared__ int sb[256];
    __shared__ int ncnt[256];
    __shared__ int ncur[256];
    int b = blockIdx.x, tid = threadIdx.x;
    if (tid < 256) {
        sb[tid] = (tid < NBUCK) ? bcnt[tid] : 0;
        ncnt[tid] = 0;
    }
    __syncthreads();
    for (int off = 1; off < 256; off <<= 1) {
        int xv = 0;
        if (tid < 256 && tid >= off) xv = sb[tid - off];
        __syncthreads();
        if (tid < 256) sb[tid] += xv;
        __syncthreads();
    }
    int n = bcnt[b];
    int base = sb[b] - n;  // exclusive prefix over buckets
    const unsigned int* reg = ebufT + (size_t)b * CAP;
    for (int i = tid; i < n; i += 1024) atomicAdd(&ncnt[reg[i] >> 16], 1);
    __syncthreads();
    int v = 0;
    if (tid < 256) {
        v = ncnt[tid];
        ncur[tid] = v;
    }
    __syncthreads();
    for (int off = 1; off < 256; off <<= 1) {
        int xv = 0;
        if (tid < 256 && tid >= off) xv = ncur[tid - off];
        __syncthreads();
        if (tid < 256) ncur[tid] += xv;
        __syncthreads();
    }
    if (tid < 256) {
        int excl = ncur[tid] - v;
        int node = b * 256 + tid;
        if (node < NODES) offs[node] = base + excl;
        ncur[tid] = excl;
    }
    __syncthreads();
    for (int i = tid; i < n; i += 1024) {
        unsigned int w = reg[i];
        int p = atomicAdd(&ncur[w >> 16], 1);
        ebuf[base + p] = (int)(w & 0xffffu);
    }
}

// ---------------- aggregation (column-split): h0[:,colOff:colOff+128] ----------------
// one wave per node; 4 groups of 16 lanes; group g handles edge j+g (16B/lane = 128 cols).
// 2 load instrs (8 edges) in flight, 2 acc banks; working set per pass = 12.8 MB (L2-friendly).
__device__ inline void upk_add(uint4 w, float* a) {
    a[0] += __uint_as_float(w.x << 16);
    a[1] += __uint_as_float(w.x & 0xffff0000u);
    a[2] += __uint_as_float(w.y << 16);
    a[3] += __uint_as_float(w.y & 0xffff0000u);
    a[4] += __uint_as_float(w.z << 16);
    a[5] += __uint_as_float(w.z & 0xffff0000u);
    a[6] += __uint_as_float(w.w << 16);
    a[7] += __uint_as_float(w.w & 0xffff0000u);
}

__global__ __launch_bounds__(256) void agg_kernel(const unsigned short* __restrict__ xb,
                                                  const int* __restrict__ offs,
                                                  const int* __restrict__ ebuf,
                                                  const float* __restrict__ eps,
                                                  unsigned short* __restrict__ h0, int colOff) {
    int wv = (blockIdx.x * 256 + threadIdx.x) >> 6;
    int lane = threadIdx.x & 63;
    if (wv >= NODES) return;
    int g = lane >> 4, l16 = lane & 15;
    const unsigned short* colBase = xb + colOff + l16 * 8;
    float aA[8] = {0, 0, 0, 0, 0, 0, 0, 0};
    float aB[8] = {0, 0, 0, 0, 0, 0, 0, 0};
    int beg = offs[wv], end = offs[wv + 1];
    int j = beg;
    for (; j + 8 <= end; j += 8) {
        int i0 = ebuf[j + g];
        int i1 = ebuf[j + 4 + g];
        uint4 w0 = *(const uint4*)(colBase + (size_t)i0 * D);
        uint4 w1 = *(const uint4*)(colBase + (size_t)i1 * D);
        upk_add(w0, aA);
        upk_add(w1, aB);
    }
    for (; j + 4 <= end; j += 4) {
        int i0 = ebuf[j + g];
        uint4 w0 = *(const uint4*)(colBase + (size_t)i0 * D);
        upk_add(w0, aA);
    }
    if (j + g < end) {
        int i0 = ebuf[j + g];
        uint4 w0 = *(const uint4*)(colBase + (size_t)i0 * D);
        upk_add(w0, aA);
    }
    float a[8];
#pragma unroll
    for (int i = 0; i < 8; i++) {
        a[i] = aA[i] + aB[i];
        a[i] += __shfl_xor(a[i], 16);
        a[i] += __shfl_xor(a[i], 32);
    }
    if (g == 0) {
        float scale = 1.0f + eps[0];
        uint4 v = *(const uint4*)(xb + (size_t)wv * D + colOff + l16 * 8);
        a[0] += scale * __uint_as_float(v.x << 16);
        a[1] += scale * __uint_as_float(v.x & 0xffff0000u);
        a[2] += scale * __uint_as_float(v.y << 16);
        a[3] += scale * __uint_as_float(v.y & 0xffff0000u);
        a[4] += scale * __uint_as_float(v.z << 16);
        a[5] += scale * __uint_as_float(v.z & 0xffff0000u);
        a[6] += scale * __uint_as_float(v.w << 16);
        a[7] += scale * __uint_as_float(v.w & 0xffff0000u);
        uint4 o;
        o.x = (unsigned int)f2b(a[0]) | ((unsigned int)f2b(a[1]) << 16);
        o.y = (unsigned int)f2b(a[2]) | ((unsigned int)f2b(a[3]) << 16);
        o.z = (unsigned int)f2b(a[4]) | ((unsigned int)f2b(a[5]) << 16);
        o.w = (unsigned int)f2b(a[6]) | ((unsigned int)f2b(a[7]) << 16);
        ((uint4*)(h0 + (size_t)wv * D + colOff))[l16] = o;
    }
}

// ---------------- fused MLP: out = relu(A@W1+b1)@W2 + b2 ----------------
// block = 4 waves, 64 rows; stage 1 -> bf16 tile in padded LDS; stage 2 -> fp32 out.
__global__ __launch_bounds__(256) void gemm_fused_kernel(const unsigned short* __restrict__ A,
                                                         const unsigned short* __restrict__ P1,
                                                         const float* __restrict__ b1,
                                                         const unsigned short* __restrict__ P2,
                                                         const float* __restrict__ b2,
                                                         float* __restrict__ out, int Mvalid) {
    __shared__ unsigned short hs[64 * HS_LD];  // 33 KB
    int wv = threadIdx.x >> 6;  // n 64-tile, 0..3
    int lane = threadIdx.x & 63;
    int quad = lane >> 4, l16 = lane & 15;
    int mBase = blockIdx.x * 64;
    const bf16x8* B1v = (const bf16x8*)P1;
    const bf16x8* B2v = (const bf16x8*)P2;

    // ---- stage 1: h = relu(A@W1+b1) -> LDS (bf16) ----
    {
        f32x4 acc[4][4] = {};
#pragma unroll
        for (int ks = 0; ks < 8; ks++) {
            bf16x8 af[4], bf[4];
#pragma unroll
            for (int mi = 0; mi < 4; mi++) {
                int row = mBase + mi * 16 + l16;
                af[mi] = *(const bf16x8*)(A + (size_t)row * D + ks * 32 + quad * 8);
            }
#pragma unroll
            for (int ni = 0; ni < 4; ni++) bf[ni] = B1v[(ks * 16 + wv * 4 + ni) * 64 + lane];
#pragma unroll
            for (int mi = 0; mi < 4; mi++)
#pragma unroll
                for (int ni = 0; ni < 4; ni++)
                    acc[mi][ni] = __builtin_amdgcn_mfma_f32_16x16x32_bf16(af[mi], bf[ni],
                                                                          acc[mi][ni], 0, 0, 0);
        }
#pragma unroll
        for (int mi = 0; mi < 4; mi++)
#pragma unroll
            for (int ni = 0; ni < 4; ni++) {
                int col = wv * 64 + ni * 16 + l16;
                float bs = b1[col];
#pragma unroll
                for (int r = 0; r < 4; r++) {
                    int rl = mi * 16 + quad * 4 + r;
                    hs[rl * HS_LD + col] = f2b(fmaxf(acc[mi][ni][r] + bs, 0.0f));
                }
            }
    }
    __syncthreads();

    // ---- stage 2: out = h@W2 + b2 (A-frags from LDS) ----
    f32x4 acc[4][4] = {};
#pragma unroll
    for (int ks = 0; ks < 8; ks++) {
        bf16x8 af[4], bf[4];
#pragma unroll
        for (int mi = 0; mi < 4; mi++)
            af[mi] = *(const bf16x8*)(hs + (mi * 16 + l16) * HS_LD + ks * 32 + quad * 8);
#pragma unroll
        for (int ni = 0; ni < 4; ni++) bf[ni] = B2v[(ks * 16 + wv * 4 + ni) * 64 + lane];
#pragma unroll
        for (int mi = 0; mi < 4; mi++)
#pragma unroll
            for (int ni = 0; ni < 4; ni++)
                acc[mi][ni] =
                    __builtin_amdgcn_mfma_f32_16x16x32_bf16(af[mi], bf[ni], acc[mi][ni], 0, 0, 0);
    }
#pragma unroll
    for (int mi = 0; mi < 4; mi++)
#pragma unroll
        for (int ni = 0; ni < 4; ni++) {
            int col = wv * 64 + ni * 16 + l16;
            float bs = b2[col];
#pragma unroll
            for (int r = 0; r < 4; r++) {
                int row = mBase + mi * 16 + quad * 4 + r;
                if (row < Mvalid) out[(size_t)row * D + col] = acc[mi][ni][r] + bs;
            }
        }
}

extern "C" void kernel_launch(void* const* d_in, const int* in_sizes, int n_in,
                              void* d_out, int out_size, void* d_ws, size_t ws_size,
                              hipStream_t stream) {
    const float* x = (const float*)d_in[0];
    const int* ei = (const int*)d_in[1];
    // d_in[2] = edge_attr, unused by forward
    const float* W1 = (const float*)d_in[3];
    const float* b1 = (const float*)d_in[4];
    const float* W2 = (const float*)d_in[5];
    const float* b2 = (const float*)d_in[6];
    const float* eps = (const float*)d_in[7];
    int E = in_sizes[1] / 2;  // 1,600,000

    char* p = (char*)d_ws;
    auto alloc = [&](size_t bytes) {
        char* r = p;
        p += (bytes + 255) & ~(size_t)255;
        return r;
    };
    unsigned short* xb = (unsigned short*)alloc((size_t)MP * D * 2);
    unsigned short* h0 = (unsigned short*)alloc((size_t)MP * D * 2);
    unsigned short* P1 = (unsigned short*)alloc(8192 * 8 * 2);
    unsigned short* P2 = (unsigned short*)alloc(8192 * 8 * 2);
    int* bcnt = (int*)alloc((size_t)NBUCK * 4);
    int* offs = (int*)alloc((size_t)(NODES + 1) * 4);
    int* ebuf = (int*)alloc((size_t)E * 4);
    unsigned int* ebufT = (unsigned int*)alloc((size_t)NBUCK * CAP * 4);

    prep_kernel<<<CAST_BLOCKS + 64, 256, 0, stream>>>(x, xb, bcnt, W1, W2, P1, P2, offs, E);
    partA_kernel<<<(E + EPB - 1) / EPB, 256, 0, stream>>>(ei, E, bcnt, ebufT);
    partB_kernel<<<NBUCK, 1024, 0, stream>>>(bcnt, ebufT, offs, ebuf);
    agg_kernel<<<(NODES + 3) / 4, 256, 0, stream>>>(xb, offs, ebuf, eps, h0, 0);
    agg_kernel<<<(NODES + 3) / 4, 256, 0, stream>>>(xb, offs, ebuf, eps, h0, 128);
    gemm_fused_kernel<<<MP / 64, 256, 0, stream>>>(h0, P1, b1, P2, b2, (float*)d_out, NODES);
}